// Round 1
// baseline (2894.191 us; speedup 1.0000x reference)
//
#include <hip/hip_runtime.h>
#include <math.h>

// Problem constants: B=32, S=1024, D=512, F=8, KN=32 knots, H=8, hd=64
// x viewed as (L=32, N=1024, D=512) for MHA (batch_first=False torch quirk).
// M = B*S = 32768 rows.

// stats buffer layout (float offsets within stats region)
#define SOFF_AMEAN 0
#define SOFF_ARSTD 512
#define SOFF_OMEAN 1024
#define SOFF_ORSTD 1536
#define SOFF_PMEAN 2048
#define SOFF_PRSTD 2056
#define SOFF_FMIN  2064
#define SOFF_FMAX  2072
#define SOFF_SMEAN 2080
#define SOFF_SRSTD 3104
#define SOFF_G1    4128
#define SOFF_GB    4136
#define SOFF_SGB   4144
#define SOFF_QGB   4145
#define SOFF_G2    4160
#define SOFF_PART  4224

// ---------------------------------------------------------------- transpose
__global__ __launch_bounds__(256) void transpose_kernel(const float* __restrict__ w,
                                                        float* __restrict__ wT) {
  int i = blockIdx.x * 256 + threadIdx.x;       // 1536*512 = 786432
  int r = i >> 9, k = i & 511;
  wT[k * 1536 + r] = w[i];
}

// ---------------------------------------------------------------- fused MHA (per n)
// qkv projection + softmax + PV, writes ctx (B,S,D) flat. No qkv materialization.
__global__ __launch_bounds__(256) void attn_kernel(const float* __restrict__ x,
    const float* __restrict__ inwT, const float* __restrict__ inb,
    float* __restrict__ ctx) {
  const int n = blockIdx.x;       // 0..1023
  const int t = threadIdx.x;
  __shared__ float xs[32 * 33];   // [l][kk] chunk (pad 33)
  __shared__ float wsm[32 * 200]; // [kk][c], c<192 = q|k|v cols (pad 200)
  __shared__ float qs[32 * 68], ks[32 * 68], vs[32 * 68];
  __shared__ float ss[32 * 33];
  const int lgrp = t >> 4, dgrp = t & 15;
  const int l0 = lgrp * 2, d0 = dgrp * 4;
  for (int h = 0; h < 8; ++h) {
    float accq[2][4], acck[2][4], accv[2][4];
#pragma unroll
    for (int li = 0; li < 2; ++li)
#pragma unroll
      for (int j = 0; j < 4; ++j) { accq[li][j] = 0.f; acck[li][j] = 0.f; accv[li][j] = 0.f; }
    const int hb = h * 64;
    for (int kk0 = 0; kk0 < 512; kk0 += 32) {
      __syncthreads();
      for (int i = t; i < 1024; i += 256) {
        int l = i >> 5, kk = i & 31;
        xs[l * 33 + kk] = x[(l * 1024 + n) * 512 + kk0 + kk];
      }
      for (int i = t; i < 6144; i += 256) {
        int kk = i / 192, c = i % 192;
        int col = (c >> 6) * 512 + hb + (c & 63);   // q:0 k:512 v:1024 blocks
        wsm[kk * 200 + c] = inwT[(kk0 + kk) * 1536 + col];
      }
      __syncthreads();
#pragma unroll 4
      for (int kk = 0; kk < 32; ++kk) {
        float a0 = xs[l0 * 33 + kk];
        float a1 = xs[(l0 + 1) * 33 + kk];
        const float* wr = &wsm[kk * 200];
        float4 wq = *(const float4*)&wr[d0];
        float4 wk = *(const float4*)&wr[64 + d0];
        float4 wv = *(const float4*)&wr[128 + d0];
        accq[0][0] += a0 * wq.x; accq[0][1] += a0 * wq.y; accq[0][2] += a0 * wq.z; accq[0][3] += a0 * wq.w;
        accq[1][0] += a1 * wq.x; accq[1][1] += a1 * wq.y; accq[1][2] += a1 * wq.z; accq[1][3] += a1 * wq.w;
        acck[0][0] += a0 * wk.x; acck[0][1] += a0 * wk.y; acck[0][2] += a0 * wk.z; acck[0][3] += a0 * wk.w;
        acck[1][0] += a1 * wk.x; acck[1][1] += a1 * wk.y; acck[1][2] += a1 * wk.z; acck[1][3] += a1 * wk.w;
        accv[0][0] += a0 * wv.x; accv[0][1] += a0 * wv.y; accv[0][2] += a0 * wv.z; accv[0][3] += a0 * wv.w;
        accv[1][0] += a1 * wv.x; accv[1][1] += a1 * wv.y; accv[1][2] += a1 * wv.z; accv[1][3] += a1 * wv.w;
      }
    }
    __syncthreads();
#pragma unroll
    for (int li = 0; li < 2; ++li) {
      int l = l0 + li;
#pragma unroll
      for (int j = 0; j < 4; ++j) {
        int d = d0 + j;
        qs[l * 68 + d] = (accq[li][j] + inb[hb + d]) * 0.125f;  // bias then 1/sqrt(64)
        ks[l * 68 + d] = acck[li][j] + inb[512 + hb + d];
        vs[l * 68 + d] = accv[li][j] + inb[1024 + hb + d];
      }
    }
    __syncthreads();
    // scores (32x32)
    for (int o = t; o < 1024; o += 256) {
      int l = o >> 5, m = o & 31;
      const float4* q4 = (const float4*)&qs[l * 68];
      const float4* k4 = (const float4*)&ks[m * 68];
      float s = 0.f;
#pragma unroll
      for (int dd = 0; dd < 16; ++dd) {
        float4 qv = q4[dd], kv = k4[dd];
        s += qv.x * kv.x + qv.y * kv.y + qv.z * kv.z + qv.w * kv.w;
      }
      ss[l * 33 + m] = s;
    }
    __syncthreads();
    if (t < 32) {  // row-wise softmax
      float mx = -3e38f;
      for (int m = 0; m < 32; ++m) mx = fmaxf(mx, ss[t * 33 + m]);
      float sum = 0.f;
      for (int m = 0; m < 32; ++m) { float e = __expf(ss[t * 33 + m] - mx); ss[t * 33 + m] = e; sum += e; }
      float inv = 1.f / sum;
      for (int m = 0; m < 32; ++m) ss[t * 33 + m] *= inv;
    }
    __syncthreads();
    // PV -> ctx
    for (int l = (t >> 4); l < 32; l += 16) {
      float4 o4; o4.x = 0.f; o4.y = 0.f; o4.z = 0.f; o4.w = 0.f;
#pragma unroll 8
      for (int m = 0; m < 32; ++m) {
        float pm = ss[l * 33 + m];
        float4 v4 = *(const float4*)&vs[m * 68 + d0];
        o4.x += pm * v4.x; o4.y += pm * v4.y; o4.z += pm * v4.z; o4.w += pm * v4.w;
      }
      *(float4*)&ctx[(l * 1024 + n) * 512 + hb + d0] = o4;
    }
  }
}

// ---------------------------------------------------------------- generic 512-K GEMM
// C[M=32768,512] = A @ W(512,512)^T + bias. grid (8, 512), block 256, 64x64 tiles.
__global__ __launch_bounds__(256) void gemm512_kernel(const float* __restrict__ A,
    const float* __restrict__ W, const float* __restrict__ bias, float* __restrict__ C) {
  __shared__ float As[16 * 68];
  __shared__ float Ws[16 * 68];
  int n0 = blockIdx.x * 64, m0 = blockIdx.y * 64;
  int t = threadIdx.x;
  int tx = t & 15, ty = t >> 4;
  float acc[4][4];
#pragma unroll
  for (int i = 0; i < 4; ++i)
#pragma unroll
    for (int j = 0; j < 4; ++j) acc[i][j] = 0.f;
  for (int k0 = 0; k0 < 512; k0 += 16) {
    __syncthreads();
    for (int i = t; i < 1024; i += 256) {
      int r = i >> 4, kk = i & 15;
      As[kk * 68 + r] = A[(m0 + r) * 512 + k0 + kk];
      Ws[kk * 68 + r] = W[(n0 + r) * 512 + k0 + kk];
    }
    __syncthreads();
#pragma unroll
    for (int kk = 0; kk < 16; ++kk) {
      float4 a = *(const float4*)&As[kk * 68 + ty * 4];
      float4 w = *(const float4*)&Ws[kk * 68 + tx * 4];
      float av[4] = {a.x, a.y, a.z, a.w};
      float wv[4] = {w.x, w.y, w.z, w.w};
#pragma unroll
      for (int i = 0; i < 4; ++i)
#pragma unroll
        for (int j = 0; j < 4; ++j) acc[i][j] += av[i] * wv[j];
    }
  }
  float4 b4 = *(const float4*)&bias[n0 + tx * 4];
#pragma unroll
  for (int i = 0; i < 4; ++i) {
    float4 o; o.x = acc[i][0] + b4.x; o.y = acc[i][1] + b4.y; o.z = acc[i][2] + b4.z; o.w = acc[i][3] + b4.w;
    *(float4*)&C[(m0 + ty * 4 + i) * 512 + n0 + tx * 4] = o;
  }
}

// ---------------------------------------------------------------- column stats, C=512
__global__ __launch_bounds__(512) void colstats_kernel(const float* __restrict__ A,
                                                       float* __restrict__ part) {
  int t = threadIdx.x;     // 512 = channel
  int blk = blockIdx.x;    // 256
  float s = 0.f, s2 = 0.f;
  for (int r = blk; r < 32768; r += 256) { float v = A[r * 512 + t]; s += v; s2 += v * v; }
  part[blk * 1024 + t] = s;
  part[blk * 1024 + 512 + t] = s2;
}
__global__ __launch_bounds__(512) void colfin_kernel(const float* __restrict__ part,
                                                     float* __restrict__ stats, int off) {
  int t = threadIdx.x;
  float s = 0.f, s2 = 0.f;
  for (int b = 0; b < 256; ++b) { s += part[b * 1024 + t]; s2 += part[b * 1024 + 512 + t]; }
  float mean = s / 32768.f;
  float var = s2 / 32768.f - mean * mean;
  stats[off + t] = mean;
  stats[off + 512 + t] = rsqrtf(var + 1e-5f);
}

// ---------------------------------------------------------------- projection (M x 8)
__global__ __launch_bounds__(256) void proj_kernel(const float* __restrict__ x,
    const float* __restrict__ pw, const float* __restrict__ pb, float* __restrict__ p) {
  int blk = blockIdx.x;  // 512 blocks * 64 rows
  int t = threadIdx.x;
  int r0 = blk * 64;
  __shared__ float xsp[64 * 33];
  __shared__ float pwc[8 * 33];
  int l = t >> 2, fg = t & 3;
  float acc0 = 0.f, acc1 = 0.f;
  for (int k0 = 0; k0 < 512; k0 += 32) {
    __syncthreads();
    for (int i = t; i < 2048; i += 256) { int ll = i >> 5, kk = i & 31; xsp[ll * 33 + kk] = x[(r0 + ll) * 512 + k0 + kk]; }
    { int ff = t >> 5, kk = t & 31; pwc[ff * 33 + kk] = pw[ff * 512 + k0 + kk]; }
    __syncthreads();
#pragma unroll 8
    for (int kk = 0; kk < 32; ++kk) {
      float xv = xsp[l * 33 + kk];
      acc0 += xv * pwc[(fg * 2) * 33 + kk];
      acc1 += xv * pwc[(fg * 2 + 1) * 33 + kk];
    }
  }
  float2 o; o.x = acc0 + pb[fg * 2]; o.y = acc1 + pb[fg * 2 + 1];
  *(float2*)&p[(r0 + l) * 8 + fg * 2] = o;
}

// ---------------------------------------------------------------- proj BN stats (C=8)
__global__ __launch_bounds__(256) void projstats_kernel(const float* __restrict__ p,
                                                        float* __restrict__ part) {
  int t = threadIdx.x, blk = blockIdx.x;  // 64 blocks
  int f = t & 7;
  float s = 0.f, s2 = 0.f;
  for (int r = blk * 32 + (t >> 3); r < 32768; r += 2048) { float v = p[r * 8 + f]; s += v; s2 += v * v; }
  __shared__ float red[256], red2[256];
  red[t] = s; red2[t] = s2; __syncthreads();
  for (int off = 128; off >= 8; off >>= 1) { if (t < off) { red[t] += red[t + off]; red2[t] += red2[t + off]; } __syncthreads(); }
  if (t < 8) { part[blk * 16 + t] = red[t]; part[blk * 16 + 8 + t] = red2[t]; }
}
__global__ void projfin_kernel(const float* __restrict__ part, float* __restrict__ stats) {
  int t = threadIdx.x;
  if (t < 8) {
    float s = 0.f, s2 = 0.f;
    for (int b = 0; b < 64; ++b) { s += part[b * 16 + t]; s2 += part[b * 16 + 8 + t]; }
    float mean = s / 32768.f;
    float var = s2 / 32768.f - mean * mean;
    stats[SOFF_PMEAN + t] = mean;
    stats[SOFF_PRSTD + t] = rsqrtf(var + 1e-5f);
  }
}

// ------------------------------------------------- apply proj-BN in place + min/max
__global__ __launch_bounds__(256) void bnminmax_kernel(float* __restrict__ p,
    const float* __restrict__ stats, const float* __restrict__ png,
    const float* __restrict__ pnb, float* __restrict__ part) {
  int t = threadIdx.x, blk = blockIdx.x;  // 64 blocks
  int i0 = blk * 256 + t;
  int f = i0 & 7;
  float k1 = stats[SOFF_PRSTD + f] * png[f];
  float k0 = pnb[f] - stats[SOFF_PMEAN + f] * k1;
  float mn = 3e38f, mx = -3e38f;
  for (int i = i0; i < 262144; i += 16384) {
    float v = p[i] * k1 + k0;
    p[i] = v;
    mn = fminf(mn, v); mx = fmaxf(mx, v);
  }
  __shared__ float rmn[256], rmx[256];
  rmn[t] = mn; rmx[t] = mx; __syncthreads();
  for (int off = 128; off >= 8; off >>= 1) {
    if (t < off) { rmn[t] = fminf(rmn[t], rmn[t + off]); rmx[t] = fmaxf(rmx[t], rmx[t + off]); }
    __syncthreads();
  }
  if (t < 8) { part[blk * 16 + t] = rmn[t]; part[blk * 16 + 8 + t] = rmx[t]; }
}
__global__ void minmaxfin_kernel(const float* __restrict__ part, float* __restrict__ stats) {
  int t = threadIdx.x;
  if (t < 8) {
    float mn = 3e38f, mx = -3e38f;
    for (int b = 0; b < 64; ++b) { mn = fminf(mn, part[b * 16 + t]); mx = fmaxf(mx, part[b * 16 + 8 + t]); }
    stats[SOFF_FMIN + t] = mn;
    stats[SOFF_FMAX + t] = mx;
  }
}

// ---------------------------------------------------------------- spline (in place)
__global__ __launch_bounds__(256) void spline_kernel(float* __restrict__ p,
    const float* __restrict__ knots, const float* __restrict__ cps,
    const float* __restrict__ stats) {
  __shared__ float ksh[8 * 33], csh[8 * 33];
  int t = threadIdx.x;
  { int f = t >> 5, j = t & 31; ksh[f * 33 + j] = knots[t]; csh[f * 33 + j] = cps[t]; }
  __syncthreads();
  int i = blockIdx.x * 256 + t;  // 262144 total
  int f = i & 7;
  float xv = p[i];
  float mn = stats[SOFF_FMIN + f], mx = stats[SOFF_FMAX + f];
  float xn = (xv - mn) / (mx - mn + 1e-6f);
  const float* kn = &ksh[f * 33];
  const float* cp = &csh[f * 33];
  int pcnt = 0;
#pragma unroll
  for (int j = 0; j < 32; ++j) pcnt += (kn[j] <= xn) ? 1 : 0;  // searchsorted 'right'
  int idx = pcnt - 1;
  idx = idx < 0 ? 0 : (idx > 30 ? 30 : idx);
  float k0v = kn[idx], k1v = kn[idx + 1];
  float tt = (xn - k0v) / (k1v - k0v);
  float val = (1.f - tt) * cp[idx] + tt * cp[idx + 1];
  bool inr = (xn >= kn[0]) && (xn <= kn[31]);
  p[i] = inr ? val : 0.f;
}

// ------------------------------------------- gate-weight Grams (for analytic BN-s)
__global__ void gateprep_kernel(const float* __restrict__ gw, const float* __restrict__ gb,
                                float* __restrict__ stats) {
  int t = threadIdx.x;  // 128 threads, serial loops (tiny)
  if (t < 64) {
    int f1 = t >> 3, f2 = t & 7; float s = 0.f;
    for (int j = 0; j < 1024; ++j) s += gw[j * 8 + f1] * gw[j * 8 + f2];
    stats[SOFF_G2 + t] = s;
  } else if (t < 72) {
    int f = t - 64; float s = 0.f;
    for (int j = 0; j < 1024; ++j) s += gw[j * 8 + f];
    stats[SOFF_G1 + f] = s;
  } else if (t < 80) {
    int f = t - 72; float s = 0.f;
    for (int j = 0; j < 1024; ++j) s += gb[j] * gw[j * 8 + f];
    stats[SOFF_GB + f] = s;
  } else if (t == 80) { float s = 0.f; for (int j = 0; j < 1024; ++j) s += gb[j]; stats[SOFF_SGB] = s; }
  else if (t == 81) { float s = 0.f; for (int j = 0; j < 1024; ++j) s += gb[j] * gb[j]; stats[SOFF_QGB] = s; }
}

// -------------------------------------- per-s BN stats of h WITHOUT materializing h
// h[b,s,j] = t[b,s,:]·gw[j,:] + gb[j]; stats over (b,j) via moments of t + Grams.
__global__ __launch_bounds__(256) void sstats_kernel(const float* __restrict__ tbuf,
                                                     float* __restrict__ stats) {
  int s = blockIdx.x, t = threadIdx.x;
  __shared__ float tv[256];
  __shared__ float red[256];
  __shared__ float T1[8];
  __shared__ float Ms[64];
  int b = t >> 3, f = t & 7;
  tv[t] = tbuf[(b * 1024 + s) * 8 + f];
  __syncthreads();
  red[t] = tv[t]; __syncthreads();
  for (int off = 128; off >= 8; off >>= 1) { if (t < off) red[t] += red[t + off]; __syncthreads(); }
  if (t < 8) T1[t] = red[t];
  if (t < 64) {
    int f1 = t >> 3, f2 = t & 7; float sM = 0.f;
    for (int bb = 0; bb < 32; ++bb) sM += tv[bb * 8 + f1] * tv[bb * 8 + f2];
    Ms[t] = sM;
  }
  __syncthreads();
  if (t == 0) {
    float sh = 0.f, s2 = 0.f;
    for (int ff = 0; ff < 8; ++ff) {
      sh += stats[SOFF_G1 + ff] * T1[ff];
      s2 += 2.f * stats[SOFF_GB + ff] * T1[ff];
    }
    sh += 32.f * stats[SOFF_SGB];
    for (int i = 0; i < 64; ++i) s2 += Ms[i] * stats[SOFF_G2 + i];
    s2 += 32.f * stats[SOFF_QGB];
    float mean = sh / 32768.f;
    float var = s2 / 32768.f - mean * mean;
    stats[SOFF_SMEAN + s] = mean;
    stats[SOFF_SRSTD + s] = rsqrtf(var + 1e-5f);
  }
}

// ------------------------------- recompute h row, BN-s, GLU, LayerNorm -> gated
__global__ __launch_bounds__(256) void gluln_kernel(const float* __restrict__ tbuf,
    const float* __restrict__ gw, const float* __restrict__ gb,
    const float* __restrict__ stats, const float* __restrict__ gbng,
    const float* __restrict__ gbnb, const float* __restrict__ lng,
    const float* __restrict__ lnb, float* __restrict__ gated) {
  int r = blockIdx.x, t = threadIdx.x, s = r & 1023;
  __shared__ float tv[8];
  __shared__ float red[256], red2[256];
  __shared__ float mr[2];
  if (t < 8) tv[t] = tbuf[r * 8 + t];
  __syncthreads();
  float t0 = tv[0], t1 = tv[1], t2 = tv[2], t3 = tv[3], t4 = tv[4], t5 = tv[5], t6 = tv[6], t7 = tv[7];
  float smean = stats[SOFF_SMEAN + s], srstd = stats[SOFF_SRSTD + s];
  float k1 = srstd * gbng[s];
  float k0 = gbnb[s] - smean * k1;   // bn(h) = h*k1 + k0  (channel = s, same for whole row)
  float hv[4];
#pragma unroll
  for (int q = 0; q < 4; ++q) {
    int j = t + q * 256;   // jA0, jA1, jB0, jB1
    float4 w0 = *(const float4*)&gw[j * 8];
    float4 w1 = *(const float4*)&gw[j * 8 + 4];
    hv[q] = t0 * w0.x + t1 * w0.y + t2 * w0.z + t3 * w0.w +
            t4 * w1.x + t5 * w1.y + t6 * w1.z + t7 * w1.w + gb[j];
    hv[q] = hv[q] * k1 + k0;
  }
  float g0 = hv[0] / (1.f + __expf(-hv[2]));
  float g1 = hv[1] / (1.f + __expf(-hv[3]));
  red[t] = g0 + g1; red2[t] = g0 * g0 + g1 * g1;
  __syncthreads();
  for (int off = 128; off > 0; off >>= 1) {
    if (t < off) { red[t] += red[t + off]; red2[t] += red2[t + off]; }
    __syncthreads();
  }
  if (t == 0) {
    float m = red[0] / 512.f;
    float v = red2[0] / 512.f - m * m;
    mr[0] = m; mr[1] = rsqrtf(v + 1e-5f);
  }
  __syncthreads();
  float m = mr[0], rs = mr[1];
  gated[r * 512 + t] = (g0 - m) * rs * lng[t] + lnb[t];
  gated[r * 512 + t + 256] = (g1 - m) * rs * lng[t + 256] + lnb[t + 256];
}

// ---------------------------------------------------------------- final elementwise
__global__ __launch_bounds__(256) void final_kernel(const float* __restrict__ x,
    const float* __restrict__ attn, const float* __restrict__ outl,
    const float* __restrict__ stats, const float* __restrict__ ag,
    const float* __restrict__ ab, const float* __restrict__ og,
    const float* __restrict__ ob, float* __restrict__ y) {
  int idx = blockIdx.x * 256 + threadIdx.x;  // 4194304 float4s
  int c4 = (idx & 127) * 4;
  float4 xv = ((const float4*)x)[idx];
  float4 av = ((const float4*)attn)[idx];
  float4 ov = ((const float4*)outl)[idx];
  float4 am = *(const float4*)&stats[SOFF_AMEAN + c4];
  float4 ar = *(const float4*)&stats[SOFF_ARSTD + c4];
  float4 om = *(const float4*)&stats[SOFF_OMEAN + c4];
  float4 orr = *(const float4*)&stats[SOFF_ORSTD + c4];
  float4 g1 = *(const float4*)&ag[c4];
  float4 b1 = *(const float4*)&ab[c4];
  float4 g2 = *(const float4*)&og[c4];
  float4 b2 = *(const float4*)&ob[c4];
  float4 o;
  o.x = xv.x + (av.x - am.x) * ar.x * g1.x + b1.x + (ov.x - om.x) * orr.x * g2.x + b2.x;
  o.y = xv.y + (av.y - am.y) * ar.y * g1.y + b1.y + (ov.y - om.y) * orr.y * g2.y + b2.y;
  o.z = xv.z + (av.z - am.z) * ar.z * g1.z + b1.z + (ov.z - om.z) * orr.z * g2.z + b2.z;
  o.w = xv.w + (av.w - am.w) * ar.w * g1.w + b1.w + (ov.w - om.w) * orr.w * g2.w + b2.w;
  ((float4*)y)[idx] = o;
}

extern "C" void kernel_launch(void* const* d_in, const int* in_sizes, int n_in,
                              void* d_out, int out_size, void* d_ws, size_t ws_size,
                              hipStream_t stream) {
  (void)in_sizes; (void)n_in; (void)out_size; (void)ws_size;
  const float* x        = (const float*)d_in[0];
  const float* in_w     = (const float*)d_in[1];
  const float* in_b     = (const float*)d_in[2];
  const float* out_w    = (const float*)d_in[3];
  const float* out_b    = (const float*)d_in[4];
  const float* attn_g   = (const float*)d_in[5];
  const float* attn_bt  = (const float*)d_in[6];
  const float* proj_w   = (const float*)d_in[7];
  const float* proj_b   = (const float*)d_in[8];
  const float* pn_g     = (const float*)d_in[9];
  const float* pn_bt    = (const float*)d_in[10];
  const float* knots    = (const float*)d_in[11];
  const float* cps      = (const float*)d_in[12];
  const float* gate_w   = (const float*)d_in[13];
  const float* gate_b   = (const float*)d_in[14];
  const float* gbn_g    = (const float*)d_in[15];
  const float* gbn_bt   = (const float*)d_in[16];
  const float* ln_g     = (const float*)d_in[17];
  const float* ln_bt    = (const float*)d_in[18];
  const float* outp_w   = (const float*)d_in[19];
  const float* outp_b   = (const float*)d_in[20];
  const float* on_g     = (const float*)d_in[21];
  const float* on_bt    = (const float*)d_in[22];

  float* ws    = (float*)d_ws;
  float* out   = (float*)d_out;
  // workspace layout (floats): ~139.5 MB total
  float* inwT  = ws;                       // 786432
  float* ctx   = inwT + 786432;            // 16777216
  float* attn  = ctx + 16777216;           // 16777216
  float* proj  = attn + 16777216;          // 262144
  float* stats = proj + 262144;            // SOFF_PART + 262144
  float* part  = stats + SOFF_PART;
  float* gated = ctx;                      // reuse ctx after attn proj done

  transpose_kernel<<<dim3(3072), dim3(256), 0, stream>>>(in_w, inwT);
  attn_kernel<<<dim3(1024), dim3(256), 0, stream>>>(x, inwT, in_b, ctx);
  gemm512_kernel<<<dim3(8, 512), dim3(256), 0, stream>>>(ctx, out_w, out_b, attn);
  colstats_kernel<<<dim3(256), dim3(512), 0, stream>>>(attn, part);
  colfin_kernel<<<dim3(1), dim3(512), 0, stream>>>(part, stats, SOFF_AMEAN);
  proj_kernel<<<dim3(512), dim3(256), 0, stream>>>(x, proj_w, proj_b, proj);
  projstats_kernel<<<dim3(64), dim3(256), 0, stream>>>(proj, part);
  projfin_kernel<<<dim3(1), dim3(64), 0, stream>>>(part, stats);
  bnminmax_kernel<<<dim3(64), dim3(256), 0, stream>>>(proj, stats, pn_g, pn_bt, part);
  minmaxfin_kernel<<<dim3(1), dim3(64), 0, stream>>>(part, stats);
  spline_kernel<<<dim3(1024), dim3(256), 0, stream>>>(proj, knots, cps, stats);
  gateprep_kernel<<<dim3(1), dim3(128), 0, stream>>>(gate_w, gate_b, stats);
  sstats_kernel<<<dim3(1024), dim3(256), 0, stream>>>(proj, stats);
  gluln_kernel<<<dim3(32768), dim3(256), 0, stream>>>(proj, gate_w, gate_b, stats,
                                                      gbn_g, gbn_bt, ln_g, ln_bt, gated);
  gemm512_kernel<<<dim3(8, 512), dim3(256), 0, stream>>>(gated, outp_w, outp_b, out);
  colstats_kernel<<<dim3(256), dim3(512), 0, stream>>>(out, part);
  colfin_kernel<<<dim3(1), dim3(512), 0, stream>>>(part, stats, SOFF_OMEAN);
  final_kernel<<<dim3(16384), dim3(256), 0, stream>>>(x, attn, out, stats,
                                                      attn_g, attn_bt, on_g, on_bt, out);
}

// Round 2
// 709.472 us; speedup vs baseline: 4.0794x; 4.0794x over previous
//
#include <hip/hip_runtime.h>
#include <math.h>

// B=32, S=1024, D=512, F=8, KN=32 knots, H=8, hd=64. M = B*S = 32768 rows.
// x (B,S,D) flat == (L=32,N=1024,D) flat for the batch_first=False MHA view.

#define SOFF_AMEAN 0
#define SOFF_ARSTD 512
#define SOFF_OMEAN 1024
#define SOFF_ORSTD 1536
#define SOFF_PMEAN 2048
#define SOFF_PRSTD 2056
#define SOFF_FMIN  2064
#define SOFF_FMAX  2072
#define SOFF_SMEAN 2080
#define SOFF_SRSTD 3104
#define SOFF_G1    4128
#define SOFF_GB    4136
#define SOFF_SGB   4144
#define SOFF_QGB   4145
#define SOFF_G2    4160
#define SOFF_PART  4224

typedef short bf16x8_t __attribute__((ext_vector_type(8)));
typedef float f32x4_t __attribute__((ext_vector_type(4)));
typedef unsigned short us8_t __attribute__((ext_vector_type(8)));

__device__ __forceinline__ unsigned short f2bf(float f) {
  unsigned u = __float_as_uint(f);
  u = (u + 0x7FFFu + ((u >> 16) & 1u)) >> 16;
  return (unsigned short)u;
}
__device__ __forceinline__ float b2f(unsigned short u) {
  return __uint_as_float(((unsigned)u) << 16);
}

// ---------------------------------------------------------------- fp32 -> bf16
__global__ __launch_bounds__(256) void cvt8_kernel(const float* __restrict__ src,
                                                   unsigned short* __restrict__ dst) {
  int i = blockIdx.x * 256 + threadIdx.x;   // one thread = 8 elems
  float4 a = ((const float4*)src)[i * 2];
  float4 b = ((const float4*)src)[i * 2 + 1];
  us8_t o;
  o[0] = f2bf(a.x); o[1] = f2bf(a.y); o[2] = f2bf(a.z); o[3] = f2bf(a.w);
  o[4] = f2bf(b.x); o[5] = f2bf(b.y); o[6] = f2bf(b.z); o[7] = f2bf(b.w);
  *(us8_t*)(dst + (size_t)i * 8) = o;
}

// ------------------------------------------------- bf16 MFMA GEMM  C = A@B^T + bias
// A (M,512) bf16 row-major, B (N,512) bf16 row-major. 128x128 tile, BK=32,
// m97 structure: global_load_lds width-16 staging, 16x16x32 MFMA, 4 waves 2x2.
template<bool OUT_BF16>
__global__ __launch_bounds__(256) void gemm_mfma_kernel(
    const unsigned short* __restrict__ A, const unsigned short* __restrict__ B,
    const float* __restrict__ bias, unsigned short* __restrict__ Cb,
    float* __restrict__ Cf, int N) {
  __shared__ unsigned short As[128 * 32];   // [row][k] 64B rows
  __shared__ unsigned short Bs[128 * 32];
  const int m0 = blockIdx.y * 128, n0 = blockIdx.x * 128;
  const int t = threadIdx.x;
  const int w = t >> 6, lane = t & 63;
  const int wm = w >> 1, wn = w & 1;
  f32x4_t acc[4][4];
#pragma unroll
  for (int i = 0; i < 4; ++i)
#pragma unroll
    for (int j = 0; j < 4; ++j) acc[i][j] = (f32x4_t){0.f, 0.f, 0.f, 0.f};

  const int lrow = lane >> 2;          // 0..15
  const int lk = (lane & 3) * 8;       // k offset of this lane's 16B
  const unsigned short* ga = A + (size_t)(m0 + w * 32 + lrow) * 512 + lk;
  const unsigned short* gb = B + (size_t)(n0 + w * 32 + lrow) * 512 + lk;
  unsigned short* lA = &As[(w * 32) * 32];
  unsigned short* lB = &Bs[(w * 32) * 32];
  const int fr = lane & 15, fq = (lane >> 4) * 8;

  for (int k0 = 0; k0 < 512; k0 += 32) {
    __syncthreads();
    __builtin_amdgcn_global_load_lds(
        (const __attribute__((address_space(1))) void*)(ga + k0),
        (__attribute__((address_space(3))) void*)lA, 16, 0, 0);
    __builtin_amdgcn_global_load_lds(
        (const __attribute__((address_space(1))) void*)(ga + k0 + 16 * 512),
        (__attribute__((address_space(3))) void*)(lA + 16 * 32), 16, 0, 0);
    __builtin_amdgcn_global_load_lds(
        (const __attribute__((address_space(1))) void*)(gb + k0),
        (__attribute__((address_space(3))) void*)lB, 16, 0, 0);
    __builtin_amdgcn_global_load_lds(
        (const __attribute__((address_space(1))) void*)(gb + k0 + 16 * 512),
        (__attribute__((address_space(3))) void*)(lB + 16 * 32), 16, 0, 0);
    __syncthreads();
    bf16x8_t af[4], bf[4];
#pragma unroll
    for (int mi = 0; mi < 4; ++mi)
      af[mi] = *(const bf16x8_t*)&As[(wm * 64 + mi * 16 + fr) * 32 + fq];
#pragma unroll
    for (int ni = 0; ni < 4; ++ni)
      bf[ni] = *(const bf16x8_t*)&Bs[(wn * 64 + ni * 16 + fr) * 32 + fq];
#pragma unroll
    for (int mi = 0; mi < 4; ++mi)
#pragma unroll
      for (int ni = 0; ni < 4; ++ni)
        acc[mi][ni] = __builtin_amdgcn_mfma_f32_16x16x32_bf16(af[mi], bf[ni], acc[mi][ni], 0, 0, 0);
  }
  // epilogue: C/D mapping col=lane&15, row=(lane>>4)*4+reg  [m89-verified]
  const int cr = (lane >> 4) * 4, cc = lane & 15;
#pragma unroll
  for (int ni = 0; ni < 4; ++ni) {
    int col = n0 + wn * 64 + ni * 16 + cc;
    float bv = bias[col];
#pragma unroll
    for (int mi = 0; mi < 4; ++mi) {
#pragma unroll
      for (int j = 0; j < 4; ++j) {
        int row = m0 + wm * 64 + mi * 16 + cr + j;
        float v = acc[mi][ni][j] + bv;
        if (OUT_BF16) Cb[(size_t)row * N + col] = f2bf(v);
        else          Cf[(size_t)row * N + col] = v;
      }
    }
  }
}

// ---------------------------------------------------------------- small attention
// qkv (32768,1536) bf16; block = one (n,h): 32x32 scores, softmax, PV -> ctx bf16.
__global__ __launch_bounds__(256) void attn2_kernel(const unsigned short* __restrict__ qkv,
                                                    unsigned short* __restrict__ ctxb) {
  const int n = blockIdx.x, h = blockIdx.y, t = threadIdx.x;
  __shared__ float qs[32 * 68], ks[32 * 68], vs[32 * 68], ss[32 * 33];
  const int l = t >> 3, j0 = (t & 7) * 8;
  size_t rowb = ((size_t)(l * 1024 + n)) * 1536 + h * 64 + j0;
  us8_t qv = *(const us8_t*)(qkv + rowb);
  us8_t kv = *(const us8_t*)(qkv + rowb + 512);
  us8_t vv = *(const us8_t*)(qkv + rowb + 1024);
#pragma unroll
  for (int j = 0; j < 8; ++j) {
    qs[l * 68 + j0 + j] = b2f(qv[j]) * 0.125f;   // 1/sqrt(64)
    ks[l * 68 + j0 + j] = b2f(kv[j]);
    vs[l * 68 + j0 + j] = b2f(vv[j]);
  }
  __syncthreads();
  for (int o = t; o < 1024; o += 256) {
    int ll = o >> 5, m = o & 31;
    const float4* q4 = (const float4*)&qs[ll * 68];
    const float4* k4 = (const float4*)&ks[m * 68];
    float s = 0.f;
#pragma unroll
    for (int dd = 0; dd < 16; ++dd) {
      float4 a = q4[dd], b = k4[dd];
      s += a.x * b.x + a.y * b.y + a.z * b.z + a.w * b.w;
    }
    ss[ll * 33 + m] = s;
  }
  __syncthreads();
  if (t < 32) {
    float mx = -3e38f;
    for (int m = 0; m < 32; ++m) mx = fmaxf(mx, ss[t * 33 + m]);
    float sum = 0.f;
    for (int m = 0; m < 32; ++m) { float e = __expf(ss[t * 33 + m] - mx); ss[t * 33 + m] = e; sum += e; }
    float inv = 1.f / sum;
    for (int m = 0; m < 32; ++m) ss[t * 33 + m] *= inv;
  }
  __syncthreads();
  float o[8] = {0.f, 0.f, 0.f, 0.f, 0.f, 0.f, 0.f, 0.f};
#pragma unroll 8
  for (int m = 0; m < 32; ++m) {
    float pm = ss[l * 33 + m];
    const float* vr = &vs[m * 68 + j0];
#pragma unroll
    for (int j = 0; j < 8; ++j) o[j] += pm * vr[j];
  }
  us8_t ov;
#pragma unroll
  for (int j = 0; j < 8; ++j) ov[j] = f2bf(o[j]);
  *(us8_t*)(ctxb + ((size_t)(l * 1024 + n)) * 512 + h * 64 + j0) = ov;
}

// ---------------------------------------------------------------- column stats, C=512
__global__ __launch_bounds__(512) void colstats_kernel(const float* __restrict__ A,
                                                       float* __restrict__ part) {
  int t = threadIdx.x, blk = blockIdx.x;  // 256 blocks
  float s = 0.f, s2 = 0.f;
  for (int r = blk; r < 32768; r += 256) { float v = A[r * 512 + t]; s += v; s2 += v * v; }
  part[blk * 1024 + t] = s;
  part[blk * 1024 + 512 + t] = s2;
}
__global__ __launch_bounds__(512) void colfin_kernel(const float* __restrict__ part,
                                                     float* __restrict__ stats, int off) {
  int t = threadIdx.x;
  float s = 0.f, s2 = 0.f;
  for (int b = 0; b < 256; ++b) { s += part[b * 1024 + t]; s2 += part[b * 1024 + 512 + t]; }
  float mean = s / 32768.f;
  float var = s2 / 32768.f - mean * mean;
  stats[off + t] = mean;
  stats[off + 512 + t] = rsqrtf(var + 1e-5f);
}

// ---------------------------------------------------------------- projection (M x 8)
__global__ __launch_bounds__(256) void proj_kernel(const float* __restrict__ x,
    const float* __restrict__ pw, const float* __restrict__ pb, float* __restrict__ p) {
  int blk = blockIdx.x, t = threadIdx.x;
  int r0 = blk * 64;
  __shared__ float xsp[64 * 33];
  __shared__ float pwc[8 * 33];
  int l = t >> 2, fg = t & 3;
  float acc0 = 0.f, acc1 = 0.f;
  for (int k0 = 0; k0 < 512; k0 += 32) {
    __syncthreads();
    for (int i = t; i < 2048; i += 256) { int ll = i >> 5, kk = i & 31; xsp[ll * 33 + kk] = x[(r0 + ll) * 512 + k0 + kk]; }
    { int ff = t >> 5, kk = t & 31; pwc[ff * 33 + kk] = pw[ff * 512 + k0 + kk]; }
    __syncthreads();
#pragma unroll 8
    for (int kk = 0; kk < 32; ++kk) {
      float xv = xsp[l * 33 + kk];
      acc0 += xv * pwc[(fg * 2) * 33 + kk];
      acc1 += xv * pwc[(fg * 2 + 1) * 33 + kk];
    }
  }
  float2 o; o.x = acc0 + pb[fg * 2]; o.y = acc1 + pb[fg * 2 + 1];
  *(float2*)&p[(r0 + l) * 8 + fg * 2] = o;
}

// ---------------------------------------------------------------- proj BN stats (C=8)
__global__ __launch_bounds__(256) void projstats_kernel(const float* __restrict__ p,
                                                        float* __restrict__ part) {
  int t = threadIdx.x, blk = blockIdx.x;  // 64 blocks
  int f = t & 7;
  float s = 0.f, s2 = 0.f;
  for (int r = blk * 32 + (t >> 3); r < 32768; r += 2048) { float v = p[r * 8 + f]; s += v; s2 += v * v; }
  __shared__ float red[256], red2[256];
  red[t] = s; red2[t] = s2; __syncthreads();
  for (int off = 128; off >= 8; off >>= 1) { if (t < off) { red[t] += red[t + off]; red2[t] += red2[t + off]; } __syncthreads(); }
  if (t < 8) { part[blk * 16 + t] = red[t]; part[blk * 16 + 8 + t] = red2[t]; }
}
__global__ void projfin_kernel(const float* __restrict__ part, float* __restrict__ stats) {
  int t = threadIdx.x;
  if (t < 8) {
    float s = 0.f, s2 = 0.f;
    for (int b = 0; b < 64; ++b) { s += part[b * 16 + t]; s2 += part[b * 16 + 8 + t]; }
    float mean = s / 32768.f;
    float var = s2 / 32768.f - mean * mean;
    stats[SOFF_PMEAN + t] = mean;
    stats[SOFF_PRSTD + t] = rsqrtf(var + 1e-5f);
  }
}

// ------------------------------------------------- apply proj-BN in place + min/max
__global__ __launch_bounds__(256) void bnminmax_kernel(float* __restrict__ p,
    const float* __restrict__ stats, const float* __restrict__ png,
    const float* __restrict__ pnb, float* __restrict__ part) {
  int t = threadIdx.x, blk = blockIdx.x;  // 64 blocks
  int i0 = blk * 256 + t;
  int f = i0 & 7;
  float k1 = stats[SOFF_PRSTD + f] * png[f];
  float k0 = pnb[f] - stats[SOFF_PMEAN + f] * k1;
  float mn = 3e38f, mx = -3e38f;
  for (int i = i0; i < 262144; i += 16384) {
    float v = p[i] * k1 + k0;
    p[i] = v;
    mn = fminf(mn, v); mx = fmaxf(mx, v);
  }
  __shared__ float rmn[256], rmx[256];
  rmn[t] = mn; rmx[t] = mx; __syncthreads();
  for (int off = 128; off >= 8; off >>= 1) {
    if (t < off) { rmn[t] = fminf(rmn[t], rmn[t + off]); rmx[t] = fmaxf(rmx[t], rmx[t + off]); }
    __syncthreads();
  }
  if (t < 8) { part[blk * 16 + t] = rmn[t]; part[blk * 16 + 8 + t] = rmx[t]; }
}
__global__ void minmaxfin_kernel(const float* __restrict__ part, float* __restrict__ stats) {
  int t = threadIdx.x;
  if (t < 8) {
    float mn = 3e38f, mx = -3e38f;
    for (int b = 0; b < 64; ++b) { mn = fminf(mn, part[b * 16 + t]); mx = fmaxf(mx, part[b * 16 + 8 + t]); }
    stats[SOFF_FMIN + t] = mn;
    stats[SOFF_FMAX + t] = mx;
  }
}

// ---------------------------------------------------------------- spline (in place)
__global__ __launch_bounds__(256) void spline_kernel(float* __restrict__ p,
    const float* __restrict__ knots, const float* __restrict__ cps,
    const float* __restrict__ stats) {
  __shared__ float ksh[8 * 33], csh[8 * 33];
  int t = threadIdx.x;
  { int f = t >> 5, j = t & 31; ksh[f * 33 + j] = knots[t]; csh[f * 33 + j] = cps[t]; }
  __syncthreads();
  int i = blockIdx.x * 256 + t;
  int f = i & 7;
  float xv = p[i];
  float mn = stats[SOFF_FMIN + f], mx = stats[SOFF_FMAX + f];
  float xn = (xv - mn) / (mx - mn + 1e-6f);
  const float* kn = &ksh[f * 33];
  const float* cp = &csh[f * 33];
  int pcnt = 0;
#pragma unroll
  for (int j = 0; j < 32; ++j) pcnt += (kn[j] <= xn) ? 1 : 0;
  int idx = pcnt - 1;
  idx = idx < 0 ? 0 : (idx > 30 ? 30 : idx);
  float k0v = kn[idx], k1v = kn[idx + 1];
  float tt = (xn - k0v) / (k1v - k0v);
  float val = (1.f - tt) * cp[idx] + tt * cp[idx + 1];
  bool inr = (xn >= kn[0]) && (xn <= kn[31]);
  p[i] = inr ? val : 0.f;
}

// ------------------------------------------- gate-weight Grams (for analytic BN-s)
__global__ void gateprep_kernel(const float* __restrict__ gw, const float* __restrict__ gb,
                                float* __restrict__ stats) {
  int t = threadIdx.x;
  if (t < 64) {
    int f1 = t >> 3, f2 = t & 7; float s = 0.f;
    for (int j = 0; j < 1024; ++j) s += gw[j * 8 + f1] * gw[j * 8 + f2];
    stats[SOFF_G2 + t] = s;
  } else if (t < 72) {
    int f = t - 64; float s = 0.f;
    for (int j = 0; j < 1024; ++j) s += gw[j * 8 + f];
    stats[SOFF_G1 + f] = s;
  } else if (t < 80) {
    int f = t - 72; float s = 0.f;
    for (int j = 0; j < 1024; ++j) s += gb[j] * gw[j * 8 + f];
    stats[SOFF_GB + f] = s;
  } else if (t == 80) { float s = 0.f; for (int j = 0; j < 1024; ++j) s += gb[j]; stats[SOFF_SGB] = s; }
  else if (t == 81) { float s = 0.f; for (int j = 0; j < 1024; ++j) s += gb[j] * gb[j]; stats[SOFF_QGB] = s; }
}

// -------------------------------------- per-s BN stats of h WITHOUT materializing h
__global__ __launch_bounds__(256) void sstats_kernel(const float* __restrict__ tbuf,
                                                     float* __restrict__ stats) {
  int s = blockIdx.x, t = threadIdx.x;
  __shared__ float tv[256];
  __shared__ float red[256];
  __shared__ float T1[8];
  __shared__ float Ms[64];
  int b = t >> 3, f = t & 7;
  tv[t] = tbuf[(b * 1024 + s) * 8 + f];
  __syncthreads();
  red[t] = tv[t]; __syncthreads();
  for (int off = 128; off >= 8; off >>= 1) { if (t < off) red[t] += red[t + off]; __syncthreads(); }
  if (t < 8) T1[t] = red[t];
  if (t < 64) {
    int f1 = t >> 3, f2 = t & 7; float sM = 0.f;
    for (int bb = 0; bb < 32; ++bb) sM += tv[bb * 8 + f1] * tv[bb * 8 + f2];
    Ms[t] = sM;
  }
  __syncthreads();
  if (t == 0) {
    float sh = 0.f, s2 = 0.f;
    for (int ff = 0; ff < 8; ++ff) {
      sh += stats[SOFF_G1 + ff] * T1[ff];
      s2 += 2.f * stats[SOFF_GB + ff] * T1[ff];
    }
    sh += 32.f * stats[SOFF_SGB];
    for (int i = 0; i < 64; ++i) s2 += Ms[i] * stats[SOFF_G2 + i];
    s2 += 32.f * stats[SOFF_QGB];
    float mean = sh / 32768.f;
    float var = s2 / 32768.f - mean * mean;
    stats[SOFF_SMEAN + s] = mean;
    stats[SOFF_SRSTD + s] = rsqrtf(var + 1e-5f);
  }
}

// ------------------------------- recompute h row, BN-s, GLU, LayerNorm -> gated bf16
__global__ __launch_bounds__(256) void gluln_kernel(const float* __restrict__ tbuf,
    const float* __restrict__ gw, const float* __restrict__ gb,
    const float* __restrict__ stats, const float* __restrict__ gbng,
    const float* __restrict__ gbnb, const float* __restrict__ lng,
    const float* __restrict__ lnb, unsigned short* __restrict__ gatedb) {
  int r = blockIdx.x, t = threadIdx.x, s = r & 1023;
  __shared__ float tv[8];
  __shared__ float red[256], red2[256];
  __shared__ float mr[2];
  if (t < 8) tv[t] = tbuf[r * 8 + t];
  __syncthreads();
  float t0 = tv[0], t1 = tv[1], t2 = tv[2], t3 = tv[3], t4 = tv[4], t5 = tv[5], t6 = tv[6], t7 = tv[7];
  float smean = stats[SOFF_SMEAN + s], srstd = stats[SOFF_SRSTD + s];
  float k1 = srstd * gbng[s];
  float k0 = gbnb[s] - smean * k1;
  float hv[4];
#pragma unroll
  for (int q = 0; q < 4; ++q) {
    int j = t + q * 256;
    float4 w0 = *(const float4*)&gw[j * 8];
    float4 w1 = *(const float4*)&gw[j * 8 + 4];
    hv[q] = t0 * w0.x + t1 * w0.y + t2 * w0.z + t3 * w0.w +
            t4 * w1.x + t5 * w1.y + t6 * w1.z + t7 * w1.w + gb[j];
    hv[q] = hv[q] * k1 + k0;
  }
  float g0 = hv[0] / (1.f + __expf(-hv[2]));
  float g1 = hv[1] / (1.f + __expf(-hv[3]));
  red[t] = g0 + g1; red2[t] = g0 * g0 + g1 * g1;
  __syncthreads();
  for (int off = 128; off > 0; off >>= 1) {
    if (t < off) { red[t] += red[t + off]; red2[t] += red2[t + off]; }
    __syncthreads();
  }
  if (t == 0) {
    float m = red[0] / 512.f;
    float v = red2[0] / 512.f - m * m;
    mr[0] = m; mr[1] = rsqrtf(v + 1e-5f);
  }
  __syncthreads();
  float m = mr[0], rs = mr[1];
  gatedb[r * 512 + t]       = f2bf((g0 - m) * rs * lng[t] + lnb[t]);
  gatedb[r * 512 + t + 256] = f2bf((g1 - m) * rs * lng[t + 256] + lnb[t + 256]);
}

// ---------------------------------------------------------------- final elementwise
__global__ __launch_bounds__(256) void final_kernel(const float* __restrict__ x,
    const float* __restrict__ attn, const float* __restrict__ outl,
    const float* __restrict__ stats, const float* __restrict__ ag,
    const float* __restrict__ ab, const float* __restrict__ og,
    const float* __restrict__ ob, float* __restrict__ y) {
  int idx = blockIdx.x * 256 + threadIdx.x;
  int c4 = (idx & 127) * 4;
  float4 xv = ((const float4*)x)[idx];
  float4 av = ((const float4*)attn)[idx];
  float4 ov = ((const float4*)outl)[idx];
  float4 am = *(const float4*)&stats[SOFF_AMEAN + c4];
  float4 ar = *(const float4*)&stats[SOFF_ARSTD + c4];
  float4 om = *(const float4*)&stats[SOFF_OMEAN + c4];
  float4 orr = *(const float4*)&stats[SOFF_ORSTD + c4];
  float4 g1 = *(const float4*)&ag[c4];
  float4 b1 = *(const float4*)&ab[c4];
  float4 g2 = *(const float4*)&og[c4];
  float4 b2 = *(const float4*)&ob[c4];
  float4 o;
  o.x = xv.x + (av.x - am.x) * ar.x * g1.x + b1.x + (ov.x - om.x) * orr.x * g2.x + b2.x;
  o.y = xv.y + (av.y - am.y) * ar.y * g1.y + b1.y + (ov.y - om.y) * orr.y * g2.y + b2.y;
  o.z = xv.z + (av.z - am.z) * ar.z * g1.z + b1.z + (ov.z - om.z) * orr.z * g2.z + b2.z;
  o.w = xv.w + (av.w - am.w) * ar.w * g1.w + b1.w + (ov.w - om.w) * orr.w * g2.w + b2.w;
  ((float4*)y)[idx] = o;
}

extern "C" void kernel_launch(void* const* d_in, const int* in_sizes, int n_in,
                              void* d_out, int out_size, void* d_ws, size_t ws_size,
                              hipStream_t stream) {
  (void)in_sizes; (void)n_in; (void)out_size; (void)ws_size;
  const float* x        = (const float*)d_in[0];
  const float* in_w     = (const float*)d_in[1];
  const float* in_b     = (const float*)d_in[2];
  const float* out_w    = (const float*)d_in[3];
  const float* out_b    = (const float*)d_in[4];
  const float* attn_g   = (const float*)d_in[5];
  const float* attn_bt  = (const float*)d_in[6];
  const float* proj_w   = (const float*)d_in[7];
  const float* proj_b   = (const float*)d_in[8];
  const float* pn_g     = (const float*)d_in[9];
  const float* pn_bt    = (const float*)d_in[10];
  const float* knots    = (const float*)d_in[11];
  const float* cps      = (const float*)d_in[12];
  const float* gate_w   = (const float*)d_in[13];
  const float* gate_b   = (const float*)d_in[14];
  const float* gbn_g    = (const float*)d_in[15];
  const float* gbn_bt   = (const float*)d_in[16];
  const float* ln_g     = (const float*)d_in[17];
  const float* ln_bt    = (const float*)d_in[18];
  const float* outp_w   = (const float*)d_in[19];
  const float* outp_b   = (const float*)d_in[20];
  const float* on_g     = (const float*)d_in[21];
  const float* on_bt    = (const float*)d_in[22];

  float* out = (float*)d_out;
  // workspace layout (~173 MB)
  unsigned short* xb      = (unsigned short*)d_ws;      // 16777216 (33.5MB)
  unsigned short* qkv_b   = xb + 16777216;              // 50331648 (100.6MB)
  unsigned short* ctx_b   = qkv_b + 50331648;           // 16777216 (33.5MB)
  unsigned short* wqkv_b  = ctx_b + 16777216;           // 786432
  unsigned short* wout_b  = wqkv_b + 786432;            // 262144
  unsigned short* woutp_b = wout_b + 262144;            // 262144
  float* proj  = (float*)(woutp_b + 262144);            // 262144 floats
  float* stats = proj + 262144;
  float* part  = stats + SOFF_PART;                     // 262144 floats
  float* attnf = (float*)qkv_b;      // alias: qkv dead after attn2
  unsigned short* gated_b = xb;      // alias: xb dead after qkv GEMM

  cvt8_kernel<<<dim3(8192), dim3(256), 0, stream>>>(x, xb);
  cvt8_kernel<<<dim3(384), dim3(256), 0, stream>>>(in_w, wqkv_b);
  cvt8_kernel<<<dim3(128), dim3(256), 0, stream>>>(out_w, wout_b);
  cvt8_kernel<<<dim3(128), dim3(256), 0, stream>>>(outp_w, woutp_b);
  // qkv = x @ in_w^T + in_b  -> bf16 (M=32768, N=1536)
  gemm_mfma_kernel<true><<<dim3(12, 256), dim3(256), 0, stream>>>(xb, wqkv_b, in_b, qkv_b, nullptr, 1536);
  attn2_kernel<<<dim3(1024, 8), dim3(256), 0, stream>>>(qkv_b, ctx_b);
  // attn_lin = ctx @ out_w^T + out_b -> fp32
  gemm_mfma_kernel<false><<<dim3(4, 256), dim3(256), 0, stream>>>(ctx_b, wout_b, out_b, nullptr, attnf, 512);
  colstats_kernel<<<dim3(256), dim3(512), 0, stream>>>(attnf, part);
  colfin_kernel<<<dim3(1), dim3(512), 0, stream>>>(part, stats, SOFF_AMEAN);
  proj_kernel<<<dim3(512), dim3(256), 0, stream>>>(x, proj_w, proj_b, proj);
  projstats_kernel<<<dim3(64), dim3(256), 0, stream>>>(proj, part);
  projfin_kernel<<<dim3(1), dim3(64), 0, stream>>>(part, stats);
  bnminmax_kernel<<<dim3(64), dim3(256), 0, stream>>>(proj, stats, pn_g, pn_bt, part);
  minmaxfin_kernel<<<dim3(1), dim3(64), 0, stream>>>(part, stats);
  spline_kernel<<<dim3(1024), dim3(256), 0, stream>>>(proj, knots, cps, stats);
  gateprep_kernel<<<dim3(1), dim3(128), 0, stream>>>(gate_w, gate_b, stats);
  sstats_kernel<<<dim3(1024), dim3(256), 0, stream>>>(proj, stats);
  gluln_kernel<<<dim3(32768), dim3(256), 0, stream>>>(proj, gate_w, gate_b, stats,
                                                      gbn_g, gbn_bt, ln_g, ln_bt, gated_b);
  // out = gated @ outp_w^T + outp_b -> fp32 (d_out)
  gemm_mfma_kernel<false><<<dim3(4, 256), dim3(256), 0, stream>>>(gated_b, woutp_b, outp_b, nullptr, out, 512);
  colstats_kernel<<<dim3(256), dim3(512), 0, stream>>>(out, part);
  colfin_kernel<<<dim3(1), dim3(512), 0, stream>>>(part, stats, SOFF_OMEAN);
  final_kernel<<<dim3(16384), dim3(256), 0, stream>>>(x, attnf, out, stats,
                                                      attn_g, attn_bt, on_g, on_bt, out);
}

// Round 4
// 520.348 us; speedup vs baseline: 5.5620x; 1.3635x over previous
//
#include <hip/hip_runtime.h>
#include <math.h>

// B=32, S=1024, D=512, F=8, KN=32 knots, H=8, hd=64. M = B*S = 32768 rows.

#define SOFF_AMEAN 0
#define SOFF_ARSTD 512
#define SOFF_OMEAN 1024
#define SOFF_ORSTD 1536
#define SOFF_PMEAN 2048
#define SOFF_PRSTD 2056
#define SOFF_FMIN  2064
#define SOFF_FMAX  2072
#define SOFF_SMEAN 2080
#define SOFF_SRSTD 3104
#define SOFF_G1    4128
#define SOFF_GB    4136
#define SOFF_SGB   4144
#define SOFF_QGB   4145
#define SOFF_G2    4160
#define SOFF_PART  4224

typedef short bf16x8_t __attribute__((ext_vector_type(8)));
typedef float f32x4_t __attribute__((ext_vector_type(4)));
typedef unsigned short us8_t __attribute__((ext_vector_type(8)));

__device__ __forceinline__ unsigned short f2bf(float f) {
  unsigned u = __float_as_uint(f);
  u = (u + 0x7FFFu + ((u >> 16) & 1u)) >> 16;
  return (unsigned short)u;
}
__device__ __forceinline__ float b2f(unsigned short u) {
  return __uint_as_float(((unsigned)u) << 16);
}

// ---------------------------------------------------------------- zero scratch
__global__ __launch_bounds__(256) void zero_kernel(float* __restrict__ p) {
  p[blockIdx.x * 256 + threadIdx.x] = 0.f;
}

// ---------------------------------------------------------------- fp32 -> bf16
__global__ __launch_bounds__(256) void cvt8_kernel(const float* __restrict__ src,
                                                   unsigned short* __restrict__ dst) {
  int i = blockIdx.x * 256 + threadIdx.x;
  float4 a = ((const float4*)src)[i * 2];
  float4 b = ((const float4*)src)[i * 2 + 1];
  us8_t o;
  o[0] = f2bf(a.x); o[1] = f2bf(a.y); o[2] = f2bf(a.z); o[3] = f2bf(a.w);
  o[4] = f2bf(b.x); o[5] = f2bf(b.y); o[6] = f2bf(b.z); o[7] = f2bf(b.w);
  *(us8_t*)(dst + (size_t)i * 8) = o;
}

// ------------------------------------------------- bf16 MFMA GEMM  C = A@B^T + bias
// 128x128 tile, BK=32, m97 structure. Linear grid NT*256, XCD-swizzled.
// STATS: per-column sum/sumsq atomically accumulated into gstats[0:512]/[512:1024].
template<int NT, bool OUT_BF16, bool STATS>
__global__ __launch_bounds__(256) void gemm_mfma_kernel(
    const unsigned short* __restrict__ A, const unsigned short* __restrict__ B,
    const float* __restrict__ bias, unsigned short* __restrict__ Cb,
    float* __restrict__ Cf, float* __restrict__ gstats, int N) {
  __shared__ unsigned short As[128 * 32];
  __shared__ unsigned short Bs[128 * 32];
  __shared__ float colred[256];
  const int bi = blockIdx.x;
  const int xcd = bi & 7, j = bi >> 3;
  const int m0 = (xcd * 32 + j / NT) * 128;
  const int n0 = (j % NT) * 128;
  const int t = threadIdx.x;
  const int w = t >> 6, lane = t & 63;
  const int wm = w >> 1, wn = w & 1;
  if (STATS) colred[t] = 0.f;
  f32x4_t acc[4][4];
#pragma unroll
  for (int i = 0; i < 4; ++i)
#pragma unroll
    for (int jj = 0; jj < 4; ++jj) acc[i][jj] = (f32x4_t){0.f, 0.f, 0.f, 0.f};

  const int lrow = lane >> 2;
  const int lk = (lane & 3) * 8;
  const unsigned short* ga = A + (size_t)(m0 + w * 32 + lrow) * 512 + lk;
  const unsigned short* gb = B + (size_t)(n0 + w * 32 + lrow) * 512 + lk;
  unsigned short* lA = &As[(w * 32) * 32];
  unsigned short* lB = &Bs[(w * 32) * 32];
  const int fr = lane & 15, fq = (lane >> 4) * 8;

  for (int k0 = 0; k0 < 512; k0 += 32) {
    __syncthreads();
    __builtin_amdgcn_global_load_lds(
        (const __attribute__((address_space(1))) void*)(ga + k0),
        (__attribute__((address_space(3))) void*)lA, 16, 0, 0);
    __builtin_amdgcn_global_load_lds(
        (const __attribute__((address_space(1))) void*)(ga + k0 + 16 * 512),
        (__attribute__((address_space(3))) void*)(lA + 16 * 32), 16, 0, 0);
    __builtin_amdgcn_global_load_lds(
        (const __attribute__((address_space(1))) void*)(gb + k0),
        (__attribute__((address_space(3))) void*)lB, 16, 0, 0);
    __builtin_amdgcn_global_load_lds(
        (const __attribute__((address_space(1))) void*)(gb + k0 + 16 * 512),
        (__attribute__((address_space(3))) void*)(lB + 16 * 32), 16, 0, 0);
    __syncthreads();
    bf16x8_t af[4], bf[4];
#pragma unroll
    for (int mi = 0; mi < 4; ++mi)
      af[mi] = *(const bf16x8_t*)&As[(wm * 64 + mi * 16 + fr) * 32 + fq];
#pragma unroll
    for (int ni = 0; ni < 4; ++ni)
      bf[ni] = *(const bf16x8_t*)&Bs[(wn * 64 + ni * 16 + fr) * 32 + fq];
#pragma unroll
    for (int mi = 0; mi < 4; ++mi)
#pragma unroll
      for (int ni = 0; ni < 4; ++ni)
        acc[mi][ni] = __builtin_amdgcn_mfma_f32_16x16x32_bf16(af[mi], bf[ni], acc[mi][ni], 0, 0, 0);
  }
  // epilogue: C/D mapping col=lane&15, row=(lane>>4)*4+reg
  const int cr = (lane >> 4) * 4, cc = lane & 15;
#pragma unroll
  for (int ni = 0; ni < 4; ++ni) {
    int col = n0 + wn * 64 + ni * 16 + cc;
    float bv = bias[col];
    float lsum = 0.f, lsq = 0.f;
#pragma unroll
    for (int mi = 0; mi < 4; ++mi) {
#pragma unroll
      for (int jj = 0; jj < 4; ++jj) {
        int row = m0 + wm * 64 + mi * 16 + cr + jj;
        float v = acc[mi][ni][jj] + bv;
        if (OUT_BF16) Cb[(size_t)row * N + col] = f2bf(v);
        else          Cf[(size_t)row * N + col] = v;
        if (STATS) { lsum += v; lsq += v * v; }
      }
    }
    if (STATS) {
      lsum += __shfl_xor(lsum, 16); lsum += __shfl_xor(lsum, 32);
      lsq  += __shfl_xor(lsq, 16);  lsq  += __shfl_xor(lsq, 32);
      if (lane < 16) {
        int cidx = wn * 64 + ni * 16 + lane;
        atomicAdd(&colred[cidx], lsum);
        atomicAdd(&colred[128 + cidx], lsq);
      }
    }
  }
  if (STATS) {
    __syncthreads();
    if (t < 128) {
      atomicAdd(&gstats[n0 + t], colred[t]);
      atomicAdd(&gstats[512 + n0 + t], colred[128 + t]);
    }
  }
}

// ------------------------------------------ finalize column stats from atomic sums
__global__ __launch_bounds__(512) void statsfin_kernel(const float* __restrict__ part,
                                                       float* __restrict__ stats, int off) {
  int t = threadIdx.x;
  float mean = part[t] / 32768.f;
  float var = part[512 + t] / 32768.f - mean * mean;
  stats[off + t] = mean;
  stats[off + 512 + t] = rsqrtf(var + 1e-5f);
}

// ---------------------------------------------------------------- small attention
__global__ __launch_bounds__(256) void attn2_kernel(const unsigned short* __restrict__ qkv,
                                                    unsigned short* __restrict__ ctxb) {
  const int n = blockIdx.x, h = blockIdx.y, t = threadIdx.x;
  __shared__ float qs[32 * 68], ks[32 * 68], vs[32 * 68], ss[32 * 33];
  const int l = t >> 3, j0 = (t & 7) * 8;
  size_t rowb = ((size_t)(l * 1024 + n)) * 1536 + h * 64 + j0;
  us8_t qv = *(const us8_t*)(qkv + rowb);
  us8_t kv = *(const us8_t*)(qkv + rowb + 512);
  us8_t vv = *(const us8_t*)(qkv + rowb + 1024);
#pragma unroll
  for (int j = 0; j < 8; ++j) {
    qs[l * 68 + j0 + j] = b2f(qv[j]) * 0.125f;
    ks[l * 68 + j0 + j] = b2f(kv[j]);
    vs[l * 68 + j0 + j] = b2f(vv[j]);
  }
  __syncthreads();
  for (int o = t; o < 1024; o += 256) {
    int ll = o >> 5, m = o & 31;
    const float4* q4 = (const float4*)&qs[ll * 68];
    const float4* k4 = (const float4*)&ks[m * 68];
    float s = 0.f;
#pragma unroll
    for (int dd = 0; dd < 16; ++dd) {
      float4 a = q4[dd], b = k4[dd];
      s += a.x * b.x + a.y * b.y + a.z * b.z + a.w * b.w;
    }
    ss[ll * 33 + m] = s;
  }
  __syncthreads();
  if (t < 32) {
    float mx = -3e38f;
    for (int m = 0; m < 32; ++m) mx = fmaxf(mx, ss[t * 33 + m]);
    float sum = 0.f;
    for (int m = 0; m < 32; ++m) { float e = __expf(ss[t * 33 + m] - mx); ss[t * 33 + m] = e; sum += e; }
    float inv = 1.f / sum;
    for (int m = 0; m < 32; ++m) ss[t * 33 + m] *= inv;
  }
  __syncthreads();
  float o[8] = {0.f, 0.f, 0.f, 0.f, 0.f, 0.f, 0.f, 0.f};
#pragma unroll 8
  for (int m = 0; m < 32; ++m) {
    float pm = ss[l * 33 + m];
    const float* vr = &vs[m * 68 + j0];
#pragma unroll
    for (int j = 0; j < 8; ++j) o[j] += pm * vr[j];
  }
  us8_t ov;
#pragma unroll
  for (int j = 0; j < 8; ++j) ov[j] = f2bf(o[j]);
  *(us8_t*)(ctxb + ((size_t)(l * 1024 + n)) * 512 + h * 64 + j0) = ov;
}

// ---------------------------------------------------------------- projection (M x 8), fp32 x
__global__ __launch_bounds__(256) void proj_kernel(const float* __restrict__ x,
    const float* __restrict__ pw, const float* __restrict__ pb, float* __restrict__ p) {
  int blk = blockIdx.x, t = threadIdx.x;
  int r0 = blk * 64;
  __shared__ float xsp[64 * 33];
  __shared__ float pwc[8 * 33];
  int l = t >> 2, fg = t & 3;
  float acc0 = 0.f, acc1 = 0.f;
  for (int k0 = 0; k0 < 512; k0 += 32) {
    __syncthreads();
    for (int i = t; i < 2048; i += 256) { int ll = i >> 5, kk = i & 31; xsp[ll * 33 + kk] = x[(size_t)(r0 + ll) * 512 + k0 + kk]; }
    { int ff = t >> 5, kk = t & 31; pwc[ff * 33 + kk] = pw[ff * 512 + k0 + kk]; }
    __syncthreads();
#pragma unroll 8
    for (int kk = 0; kk < 32; ++kk) {
      float xv = xsp[l * 33 + kk];
      acc0 += xv * pwc[(fg * 2) * 33 + kk];
      acc1 += xv * pwc[(fg * 2 + 1) * 33 + kk];
    }
  }
  float2 o; o.x = acc0 + pb[fg * 2]; o.y = acc1 + pb[fg * 2 + 1];
  *(float2*)&p[(r0 + l) * 8 + fg * 2] = o;
}

// ---------------------------------------------------------------- proj BN stats (C=8)
__global__ __launch_bounds__(256) void projstats_kernel(const float* __restrict__ p,
                                                        float* __restrict__ part) {
  int t = threadIdx.x, blk = blockIdx.x;  // 64 blocks
  int f = t & 7;
  float s = 0.f, s2 = 0.f;
  for (int r = blk * 32 + (t >> 3); r < 32768; r += 2048) { float v = p[r * 8 + f]; s += v; s2 += v * v; }
  __shared__ float red[256], red2[256];
  red[t] = s; red2[t] = s2; __syncthreads();
  for (int off = 128; off >= 8; off >>= 1) { if (t < off) { red[t] += red[t + off]; red2[t] += red2[t + off]; } __syncthreads(); }
  if (t < 8) { part[blk * 16 + t] = red[t]; part[blk * 16 + 8 + t] = red2[t]; }
}
__global__ void projfin_kernel(const float* __restrict__ part, float* __restrict__ stats) {
  int t = threadIdx.x;
  if (t < 8) {
    float s = 0.f, s2 = 0.f;
    for (int b = 0; b < 64; ++b) { s += part[b * 16 + t]; s2 += part[b * 16 + 8 + t]; }
    float mean = s / 32768.f;
    float var = s2 / 32768.f - mean * mean;
    stats[SOFF_PMEAN + t] = mean;
    stats[SOFF_PRSTD + t] = rsqrtf(var + 1e-5f);
  }
}

// ------------------------------------------------- apply proj-BN in place + min/max
__global__ __launch_bounds__(256) void bnminmax_kernel(float* __restrict__ p,
    const float* __restrict__ stats, const float* __restrict__ png,
    const float* __restrict__ pnb, float* __restrict__ part) {
  int t = threadIdx.x, blk = blockIdx.x;  // 64 blocks
  int i0 = blk * 256 + t;
  int f = i0 & 7;
  float k1 = stats[SOFF_PRSTD + f] * png[f];
  float k0 = pnb[f] - stats[SOFF_PMEAN + f] * k1;
  float mn = 3e38f, mx = -3e38f;
  for (int i = i0; i < 262144; i += 16384) {
    float v = p[i] * k1 + k0;
    p[i] = v;
    mn = fminf(mn, v); mx = fmaxf(mx, v);
  }
  __shared__ float rmn[256], rmx[256];
  rmn[t] = mn; rmx[t] = mx; __syncthreads();
  for (int off = 128; off >= 8; off >>= 1) {
    if (t < off) { rmn[t] = fminf(rmn[t], rmn[t + off]); rmx[t] = fmaxf(rmx[t], rmx[t + off]); }
    __syncthreads();
  }
  if (t < 8) { part[blk * 16 + t] = rmn[t]; part[blk * 16 + 8 + t] = rmx[t]; }
}
__global__ void minmaxfin_kernel(const float* __restrict__ part, float* __restrict__ stats) {
  int t = threadIdx.x;
  if (t < 8) {
    float mn = 3e38f, mx = -3e38f;
    for (int b = 0; b < 64; ++b) { mn = fminf(mn, part[b * 16 + t]); mx = fmaxf(mx, part[b * 16 + 8 + t]); }
    stats[SOFF_FMIN + t] = mn;
    stats[SOFF_FMAX + t] = mx;
  }
}

// ---------------------------------------------------------------- spline (in place)
__global__ __launch_bounds__(256) void spline_kernel(float* __restrict__ p,
    const float* __restrict__ knots, const float* __restrict__ cps,
    const float* __restrict__ stats) {
  __shared__ float ksh[8 * 33], csh[8 * 33];
  int t = threadIdx.x;
  { int f = t >> 5, j = t & 31; ksh[f * 33 + j] = knots[t]; csh[f * 33 + j] = cps[t]; }
  __syncthreads();
  int i = blockIdx.x * 256 + t;
  int f = i & 7;
  float xv = p[i];
  float mn = stats[SOFF_FMIN + f], mx = stats[SOFF_FMAX + f];
  float xn = (xv - mn) / (mx - mn + 1e-6f);
  const float* kn = &ksh[f * 33];
  const float* cp = &csh[f * 33];
  int pcnt = 0;
#pragma unroll
  for (int j = 0; j < 32; ++j) pcnt += (kn[j] <= xn) ? 1 : 0;
  int idx = pcnt - 1;
  idx = idx < 0 ? 0 : (idx > 30 ? 30 : idx);
  float k0v = kn[idx], k1v = kn[idx + 1];
  float tt = (xn - k0v) / (k1v - k0v);
  float val = (1.f - tt) * cp[idx] + tt * cp[idx + 1];
  bool inr = (xn >= kn[0]) && (xn <= kn[31]);
  p[i] = inr ? val : 0.f;
}

// ------------------------------------------- gate-weight Grams (parallel, 88 blocks)
__global__ __launch_bounds__(256) void gateprep_kernel(const float* __restrict__ gw,
    const float* __restrict__ gb, float* __restrict__ stats) {
  int b = blockIdx.x, t = threadIdx.x;
  __shared__ float red[256];
  float s = 0.f;
  if (b < 64) {
    int f1 = b >> 3, f2 = b & 7;
    for (int j = t; j < 1024; j += 256) s += gw[j * 8 + f1] * gw[j * 8 + f2];
  } else if (b < 72) {
    int f = b - 64;
    for (int j = t; j < 1024; j += 256) s += gw[j * 8 + f];
  } else if (b < 80) {
    int f = b - 72;
    for (int j = t; j < 1024; j += 256) s += gb[j] * gw[j * 8 + f];
  } else if (b == 80) {
    for (int j = t; j < 1024; j += 256) s += gb[j];
  } else {
    for (int j = t; j < 1024; j += 256) s += gb[j] * gb[j];
  }
  red[t] = s; __syncthreads();
  for (int off = 128; off > 0; off >>= 1) { if (t < off) red[t] += red[t + off]; __syncthreads(); }
  if (t == 0) {
    float v = red[0];
    if (b < 64) stats[SOFF_G2 + b] = v;
    else if (b < 72) stats[SOFF_G1 + (b - 64)] = v;
    else if (b < 80) stats[SOFF_GB + (b - 72)] = v;
    else if (b == 80) stats[SOFF_SGB] = v;
    else stats[SOFF_QGB] = v;
  }
}

// -------------------------------------- per-s BN stats of h WITHOUT materializing h
__global__ __launch_bounds__(256) void sstats_kernel(const float* __restrict__ tbuf,
                                                     float* __restrict__ stats) {
  int s = blockIdx.x, t = threadIdx.x;
  __shared__ float tv[256];
  __shared__ float red[256];
  __shared__ float T1[8];
  __shared__ float Ms[64];
  int b = t >> 3, f = t & 7;
  tv[t] = tbuf[(b * 1024 + s) * 8 + f];
  __syncthreads();
  red[t] = tv[t]; __syncthreads();
  for (int off = 128; off >= 8; off >>= 1) { if (t < off) red[t] += red[t + off]; __syncthreads(); }
  if (t < 8) T1[t] = red[t];
  if (t < 64) {
    int f1 = t >> 3, f2 = t & 7; float sM = 0.f;
    for (int bb = 0; bb < 32; ++bb) sM += tv[bb * 8 + f1] * tv[bb * 8 + f2];
    Ms[t] = sM;
  }
  __syncthreads();
  if (t == 0) {
    float sh = 0.f, s2 = 0.f;
    for (int ff = 0; ff < 8; ++ff) {
      sh += stats[SOFF_G1 + ff] * T1[ff];
      s2 += 2.f * stats[SOFF_GB + ff] * T1[ff];
    }
    sh += 32.f * stats[SOFF_SGB];
    for (int i = 0; i < 64; ++i) s2 += Ms[i] * stats[SOFF_G2 + i];
    s2 += 32.f * stats[SOFF_QGB];
    float mean = sh / 32768.f;
    float var = s2 / 32768.f - mean * mean;
    stats[SOFF_SMEAN + s] = mean;
    stats[SOFF_SRSTD + s] = rsqrtf(var + 1e-5f);
  }
}

// ---- recompute h row (fp32 gate_w — MUST match sstats' weights), BN-s, GLU, LN
__global__ __launch_bounds__(256) void gluln_kernel(const float* __restrict__ tbuf,
    const float* __restrict__ gw, const float* __restrict__ gb,
    const float* __restrict__ stats, const float* __restrict__ gbng,
    const float* __restrict__ gbnb, const float* __restrict__ lng,
    const float* __restrict__ lnb, unsigned short* __restrict__ gatedb) {
  const int t = threadIdx.x, wave = t >> 6, lane = t & 63;
  for (int rr = 0; rr < 4; ++rr) {
    const int r = blockIdx.x * 16 + wave * 4 + rr;
    const int s = r & 1023;
    float4 tA = *(const float4*)&tbuf[r * 8];
    float4 tB = *(const float4*)&tbuf[r * 8 + 4];
    float smean = stats[SOFF_SMEAN + s], srstd = stats[SOFF_SRSTD + s];
    float k1 = srstd * gbng[s];
    float k0 = gbnb[s] - smean * k1;
    float g[8];
    float sum = 0.f, sq = 0.f;
#pragma unroll
    for (int i = 0; i < 8; ++i) {
      int c = i * 64 + lane;
      float4 wa0 = *(const float4*)&gw[c * 8];
      float4 wa1 = *(const float4*)&gw[c * 8 + 4];
      float4 wb0 = *(const float4*)&gw[(c + 512) * 8];
      float4 wb1 = *(const float4*)&gw[(c + 512) * 8 + 4];
      float ha = tA.x * wa0.x + tA.y * wa0.y + tA.z * wa0.z + tA.w * wa0.w
               + tB.x * wa1.x + tB.y * wa1.y + tB.z * wa1.z + tB.w * wa1.w + gb[c];
      float hb = tA.x * wb0.x + tA.y * wb0.y + tA.z * wb0.z + tA.w * wb0.w
               + tB.x * wb1.x + tB.y * wb1.y + tB.z * wb1.z + tB.w * wb1.w + gb[c + 512];
      ha = ha * k1 + k0;
      hb = hb * k1 + k0;
      float gv = ha / (1.f + __expf(-hb));
      g[i] = gv; sum += gv; sq += gv * gv;
    }
#pragma unroll
    for (int m = 32; m >= 1; m >>= 1) { sum += __shfl_xor(sum, m); sq += __shfl_xor(sq, m); }
    float mean = sum * (1.f / 512.f);
    float rstd = rsqrtf(sq * (1.f / 512.f) - mean * mean + 1e-5f);
#pragma unroll
    for (int i = 0; i < 8; ++i) {
      int c = i * 64 + lane;
      gatedb[(size_t)r * 512 + c] = f2bf((g[i] - mean) * rstd * lng[c] + lnb[c]);
    }
  }
}

// ---------------------------------------------------------------- final elementwise
__global__ __launch_bounds__(256) void final_kernel(const float* __restrict__ x,
    const float* __restrict__ attn, const float* __restrict__ outl,
    const float* __restrict__ stats, const float* __restrict__ ag,
    const float* __restrict__ ab, const float* __restrict__ og,
    const float* __restrict__ ob, float* __restrict__ y) {
  int idx = blockIdx.x * 256 + threadIdx.x;
  int c4 = (idx & 127) * 4;
  float4 xv = ((const float4*)x)[idx];
  float4 av = ((const float4*)attn)[idx];
  float4 ov = ((const float4*)outl)[idx];
  float4 am = *(const float4*)&stats[SOFF_AMEAN + c4];
  float4 ar = *(const float4*)&stats[SOFF_ARSTD + c4];
  float4 om = *(const float4*)&stats[SOFF_OMEAN + c4];
  float4 orr = *(const float4*)&stats[SOFF_ORSTD + c4];
  float4 g1 = *(const float4*)&ag[c4];
  float4 b1 = *(const float4*)&ab[c4];
  float4 g2 = *(const float4*)&og[c4];
  float4 b2 = *(const float4*)&ob[c4];
  float4 o;
  o.x = xv.x + (av.x - am.x) * ar.x * g1.x + b1.x + (ov.x - om.x) * orr.x * g2.x + b2.x;
  o.y = xv.y + (av.y - am.y) * ar.y * g1.y + b1.y + (ov.y - om.y) * orr.y * g2.y + b2.y;
  o.z = xv.z + (av.z - am.z) * ar.z * g1.z + b1.z + (ov.z - om.z) * orr.z * g2.z + b2.z;
  o.w = xv.w + (av.w - am.w) * ar.w * g1.w + b1.w + (ov.w - om.w) * orr.w * g2.w + b2.w;
  ((float4*)y)[idx] = o;
}

extern "C" void kernel_launch(void* const* d_in, const int* in_sizes, int n_in,
                              void* d_out, int out_size, void* d_ws, size_t ws_size,
                              hipStream_t stream) {
  (void)in_sizes; (void)n_in; (void)out_size; (void)ws_size;
  const float* x        = (const float*)d_in[0];
  const float* in_w     = (const float*)d_in[1];
  const float* in_b     = (const float*)d_in[2];
  const float* out_w    = (const float*)d_in[3];
  const float* out_b    = (const float*)d_in[4];
  const float* attn_g   = (const float*)d_in[5];
  const float* attn_bt  = (const float*)d_in[6];
  const float* proj_w   = (const float*)d_in[7];
  const float* proj_b   = (const float*)d_in[8];
  const float* pn_g     = (const float*)d_in[9];
  const float* pn_bt    = (const float*)d_in[10];
  const float* knots    = (const float*)d_in[11];
  const float* cps      = (const float*)d_in[12];
  const float* gate_w   = (const float*)d_in[13];
  const float* gate_b   = (const float*)d_in[14];
  const float* gbn_g    = (const float*)d_in[15];
  const float* gbn_bt   = (const float*)d_in[16];
  const float* ln_g     = (const float*)d_in[17];
  const float* ln_bt    = (const float*)d_in[18];
  const float* outp_w   = (const float*)d_in[19];
  const float* outp_b   = (const float*)d_in[20];
  const float* on_g     = (const float*)d_in[21];
  const float* on_bt    = (const float*)d_in[22];

  float* out = (float*)d_out;
  unsigned short* xb      = (unsigned short*)d_ws;      // 16777216
  unsigned short* qkv_b   = xb + 16777216;              // 50331648
  unsigned short* ctx_b   = qkv_b + 50331648;           // 16777216
  unsigned short* wqkv_b  = ctx_b + 16777216;           // 786432
  unsigned short* wout_b  = wqkv_b + 786432;            // 262144
  unsigned short* woutp_b = wout_b + 262144;            // 262144
  float* proj  = (float*)(woutp_b + 262144);            // 262144 floats
  float* stats = proj + 262144;
  float* part  = stats + SOFF_PART;                     // 4096 floats
  float* partA  = part;                                 // 1024 (atomic col stats attn)
  float* partO  = part + 1024;                          // 1024 (atomic col stats out)
  float* partP  = part + 2048;                          // 1024 (projstats partials)
  float* partMM = part + 3072;                          // 1024 (minmax partials)
  float* attnf = (float*)qkv_b;      // alias: qkv dead after attn2
  unsigned short* gated_b = xb;      // alias: xb dead after qkv GEMM

  zero_kernel<<<dim3(8), dim3(256), 0, stream>>>(part);   // partA+partO
  cvt8_kernel<<<dim3(8192), dim3(256), 0, stream>>>(x, xb);
  cvt8_kernel<<<dim3(384), dim3(256), 0, stream>>>(in_w, wqkv_b);
  cvt8_kernel<<<dim3(128), dim3(256), 0, stream>>>(out_w, wout_b);
  cvt8_kernel<<<dim3(128), dim3(256), 0, stream>>>(outp_w, woutp_b);
  // qkv = x @ in_w^T + in_b -> bf16
  gemm_mfma_kernel<12, true, false><<<dim3(3072), dim3(256), 0, stream>>>(
      xb, wqkv_b, in_b, qkv_b, nullptr, nullptr, 1536);
  attn2_kernel<<<dim3(1024, 8), dim3(256), 0, stream>>>(qkv_b, ctx_b);
  // attn_lin = ctx @ out_w^T + out_b -> fp32 (+ fused column stats)
  gemm_mfma_kernel<4, false, true><<<dim3(1024), dim3(256), 0, stream>>>(
      ctx_b, wout_b, out_b, nullptr, attnf, partA, 512);
  statsfin_kernel<<<dim3(1), dim3(512), 0, stream>>>(partA, stats, SOFF_AMEAN);
  proj_kernel<<<dim3(512), dim3(256), 0, stream>>>(x, proj_w, proj_b, proj);
  projstats_kernel<<<dim3(64), dim3(256), 0, stream>>>(proj, partP);
  projfin_kernel<<<dim3(1), dim3(64), 0, stream>>>(partP, stats);
  bnminmax_kernel<<<dim3(64), dim3(256), 0, stream>>>(proj, stats, pn_g, pn_bt, partMM);
  minmaxfin_kernel<<<dim3(1), dim3(64), 0, stream>>>(partMM, stats);
  spline_kernel<<<dim3(1024), dim3(256), 0, stream>>>(proj, knots, cps, stats);
  gateprep_kernel<<<dim3(88), dim3(256), 0, stream>>>(gate_w, gate_b, stats);
  sstats_kernel<<<dim3(1024), dim3(256), 0, stream>>>(proj, stats);
  gluln_kernel<<<dim3(2048), dim3(256), 0, stream>>>(proj, gate_w, gate_b, stats,
                                                     gbn_g, gbn_bt, ln_g, ln_bt, gated_b);
  // out = gated @ outp_w^T + outp_b -> fp32 (+ fused column stats)
  gemm_mfma_kernel<4, false, true><<<dim3(1024), dim3(256), 0, stream>>>(
      gated_b, woutp_b, outp_b, nullptr, out, partO, 512);
  statsfin_kernel<<<dim3(1), dim3(512), 0, stream>>>(partO, stats, SOFF_OMEAN);
  final_kernel<<<dim3(16384), dim3(256), 0, stream>>>(x, attnf, out, stats,
                                                      attn_g, attn_bt, on_g, on_bt, out);
}